// Round 4
// baseline (213.618 us; speedup 1.0000x reference)
//
#include <hip/hip_runtime.h>

#define IN_DIM   16384
#define OUT_DIM  16384
#define BATCH    64
#define K_IN     1024
#define NPAIRS   65536
#define CAP      64        // bucket capacity per row (Poisson lambda=4, P(>64)~0)
#define NBLK     256       // persistent blocks, 1 per CU
#define NCONS    6         // consumer waves per block
#define NPROD    2         // producer waves per block

// ---------------- prep ------------------------------------------------------

__global__ void zero_kernel(int* __restrict__ p, int n) {
    int i = blockIdx.x * blockDim.x + threadIdx.x;
    if (i < n) p[i] = 0;
}

__global__ void scatter_kernel(const int* __restrict__ out_idx,
                               int* __restrict__ cursor,
                               int* __restrict__ pairs) {
    int t = blockIdx.x * blockDim.x + threadIdx.x;
    int r = out_idx[t];
    int pos = atomicAdd(&cursor[r], 1);
    if (pos < CAP) pairs[r * CAP + pos] = t;
}

__global__ void rowlist_kernel(const int* __restrict__ cursor,
                               int* __restrict__ rowlist,
                               int* __restrict__ nrows) {
    int r = blockIdx.x * blockDim.x + threadIdx.x;
    if (cursor[r] > 0) {
        int p = atomicAdd(nrows, 1);
        rowlist[p] = r;       // order nondeterministic; outputs unaffected
    }
}

// ---------------- main: persistent producer/consumer pipeline ---------------
// 1 block/CU, 128 KB LDS double-buffer. Producer waves stream row i+1 while
// consumer waves compute row i. Counted vmcnt keeps the stage in flight
// across barriers; consumers' plain loads live in their own clean vmcnt FIFO.

__launch_bounds__(512)
__global__ void slide_main(const float* __restrict__ in_vals,
                           const float* __restrict__ W,
                           const float* __restrict__ bias,
                           const int*   __restrict__ in_idx,
                           const int*   __restrict__ cnts,
                           const int*   __restrict__ pairs,
                           const int*   __restrict__ rowlist,
                           const int*   __restrict__ nrows_p,
                           float*       __restrict__ out) {
    __shared__ float buf[2][IN_DIM];            // 2 x 64 KB
    int c    = blockIdx.x;
    int w    = threadIdx.x >> 6;                // wave 0..7
    int lane = threadIdx.x & 63;
    int nrows = nrows_p[0];
    if (c >= nrows) return;
    int my = (nrows - c + NBLK - 1) / NBLK;     // rows for this block

    bool producer = (w >= NCONS);
    int  pw       = w - NCONS;                  // 0..1

    // prologue: stage row 0 into buf[0]
    int r = rowlist[c];
    if (producer) {
        const float* g = W + (size_t)r * IN_DIM;
        #pragma unroll
        for (int k = 0; k < 32; ++k) {
            int ch = k * NPROD + pw;            // chunk 0..63, 1 KB each
            __builtin_amdgcn_global_load_lds(
                (const __attribute__((address_space(1))) void*)(g + ch * 256 + lane * 4),
                (__attribute__((address_space(3))) void*)(&buf[0][ch * 256]),
                16, 0, 0);
        }
    }

    for (int i = 0; i < my; ++i) {
        int hn = (i + 1 < my);
        int rn = hn ? rowlist[c + (i + 1) * NBLK] : 0;

        if (producer) {
            if (hn) {
                // issue next row's stage, then wait only for the CURRENT row
                const float* g   = W + (size_t)rn * IN_DIM;
                float*       dst = buf[(i + 1) & 1];
                #pragma unroll
                for (int k = 0; k < 32; ++k) {
                    int ch = k * NPROD + pw;
                    __builtin_amdgcn_global_load_lds(
                        (const __attribute__((address_space(1))) void*)(g + ch * 256 + lane * 4),
                        (__attribute__((address_space(3))) void*)(dst + ch * 256),
                        16, 0, 0);
                }
                asm volatile("s_waitcnt vmcnt(32)" ::: "memory"); // keep 32 newest in flight
            } else {
                asm volatile("s_waitcnt vmcnt(0)" ::: "memory");
            }
            __builtin_amdgcn_sched_barrier(0);
            __builtin_amdgcn_s_barrier();       // buf[i&1] ready
            __builtin_amdgcn_s_barrier();       // consumers done with buf[i&1]
        } else {
            asm volatile("" ::: "memory");
            __builtin_amdgcn_s_barrier();       // wait: buf[i&1] ready
            asm volatile("" ::: "memory");

            const float* row  = buf[i & 1];
            int          cnt  = cnts[r];
            const int*   prow = pairs + r * CAP;
            float        bv   = bias[r];

            for (int p = w; p < cnt; p += NCONS) {
                int t  = prow[p];
                int bb = t >> 10;
                const int4*   idx4 = (const int4*)  (in_idx  + bb * K_IN);
                const float4* val4 = (const float4*)(in_vals + bb * K_IN);

                float acc = 0.f;
                #pragma unroll
                for (int q = 0; q < 4; ++q) {
                    int4   id = idx4[lane + q * 64];     // coalesced, L2-hot
                    float4 v  = val4[lane + q * 64];
                    acc += row[id.x] * v.x + row[id.y] * v.y
                         + row[id.z] * v.z + row[id.w] * v.w;
                }
                #pragma unroll
                for (int m = 32; m >= 1; m >>= 1) acc += __shfl_xor(acc, m, 64);
                if (lane == 0) out[t] = acc + bv;
            }
            asm volatile("" ::: "memory");
            __builtin_amdgcn_s_barrier();       // release buf[i&1] for overwrite
        }
        r = rn;
    }
}

// ---------------------------------------------------------------------------

extern "C" void kernel_launch(void* const* d_in, const int* in_sizes, int n_in,
                              void* d_out, int out_size, void* d_ws, size_t ws_size,
                              hipStream_t stream) {
    const float* in_vals = (const float*)d_in[0];   // (64,1024) f32
    const float* W       = (const float*)d_in[1];   // (16384,16384) f32
    const float* bias    = (const float*)d_in[2];   // (16384,) f32
    const int*   in_idx  = (const int*)  d_in[3];   // (64,1024) i32
    const int*   out_idx = (const int*)  d_in[4];   // (64,1024) i32
    float*       out     = (float*)d_out;           // (64,1024) f32

    // workspace (ints): cursor[OUT_DIM] | nrows[16] | rowlist[OUT_DIM] | pairs[OUT_DIM*CAP]
    int* cursor  = (int*)d_ws;
    int* nrows   = cursor + OUT_DIM;
    int* rowlist = nrows + 16;
    int* pairs   = rowlist + OUT_DIM;

    zero_kernel   <<<(OUT_DIM + 16 + 255) / 256, 256, 0, stream>>>(cursor, OUT_DIM + 16);
    scatter_kernel<<<NPAIRS / 256, 256, 0, stream>>>(out_idx, cursor, pairs);
    rowlist_kernel<<<OUT_DIM / 256, 256, 0, stream>>>(cursor, rowlist, nrows);
    slide_main    <<<NBLK, 512, 0, stream>>>(in_vals, W, bias, in_idx,
                                             cursor, pairs, rowlist, nrows, out);
}

// Round 5
// 212.933 us; speedup vs baseline: 1.0032x; 1.0032x over previous
//
#include <hip/hip_runtime.h>

#define IN_DIM   16384
#define OUT_DIM  16384
#define BATCH    64
#define K_IN     1024
#define NPAIRS   65536
#define CAP      64        // bucket capacity per row (Poisson lambda=4)
#define HALF     8192      // floats per half-row
#define LISTCAP  1024      // per-batch per-half padded list capacity

// ---------------- prep ------------------------------------------------------

__global__ void zero_kernel(int* __restrict__ p, int n) {
    int i = blockIdx.x * blockDim.x + threadIdx.x;
    if (i < n) p[i] = 0;
}

__global__ void scatter_kernel(const int* __restrict__ out_idx,
                               int* __restrict__ cursor,
                               int* __restrict__ pairs) {
    int t = blockIdx.x * blockDim.x + threadIdx.x;
    int r = out_idx[t];
    int pos = atomicAdd(&cursor[r], 1);
    if (pos < CAP) pairs[r * CAP + pos] = t;
}

// one wave per batch: stable partition of (idx,val) into lo/hi half lists,
// hi indices pre-biased by -HALF, both lists zero-padded to x256.
__global__ void partition_kernel(const int*   __restrict__ in_idx,
                                 const float* __restrict__ in_vals,
                                 int*   __restrict__ lo_idx, float* __restrict__ lo_val,
                                 int*   __restrict__ hi_idx, float* __restrict__ hi_val,
                                 int*   __restrict__ nq) {   // nq[2*b+h] = #256-chunks
    int b    = blockIdx.x;
    int lane = threadIdx.x;                 // blockDim == 64
    const int*   idx = in_idx  + b * K_IN;
    const float* val = in_vals + b * K_IN;
    int*   lod = lo_idx + b * LISTCAP;  float* lov = lo_val + b * LISTCAP;
    int*   hid = hi_idx + b * LISTCAP;  float* hiv = hi_val + b * LISTCAP;

    unsigned long long below = (lane == 63) ? ~0ull >> 1
                             : (1ull << lane) - 1;
    int nlo = 0, nhi = 0;
    for (int c = 0; c < K_IN / 64; ++c) {
        int   id = idx[c * 64 + lane];
        float v  = val[c * 64 + lane];
        bool  lo = id < HALF;
        unsigned long long m = __ballot(lo);
        if (lo) { int p = nlo + __popcll(m  & below); lod[p] = id;        lov[p] = v; }
        else    { int p = nhi + __popcll(~m & below); hid[p] = id - HALF; hiv[p] = v; }
        nlo += __popcll(m);
        nhi  = (c + 1) * 64 - nlo;
    }
    int plo = (nlo + 255) & ~255, phi = (nhi + 255) & ~255;
    for (int i = nlo + lane; i < plo; i += 64) { lod[i] = 0; lov[i] = 0.f; }
    for (int i = nhi + lane; i < phi; i += 64) { hid[i] = 0; hiv[i] = 0.f; }
    if (lane == 0) { nq[2 * b] = plo >> 8; nq[2 * b + 1] = phi >> 8; }
}

// ---------------- main: one block per (row, half), 32 KB LDS ----------------
// 5 blocks/CU so per-row vmcnt drains and launch gaps interleave; each block
// gathers only its half's compacted list (total gather work == full-row case).

__launch_bounds__(256)
__global__ void slide_main(const float* __restrict__ W,
                           const int*   __restrict__ cnts,
                           const int*   __restrict__ pairs,
                           const int*   __restrict__ lo_idx, const float* __restrict__ lo_val,
                           const int*   __restrict__ hi_idx, const float* __restrict__ hi_val,
                           const int*   __restrict__ nq,
                           float*       __restrict__ part) {
    __shared__ float row[HALF];             // 32 KB
    int blk = blockIdx.x;
    int r   = blk >> 1;
    int h   = blk & 1;
    int cnt = cnts[r];
    if (cnt == 0) return;

    int w    = threadIdx.x >> 6;            // wave 0..3
    int lane = threadIdx.x & 63;

    const float* g = W + (size_t)r * IN_DIM + h * HALF;
    #pragma unroll
    for (int k = 0; k < 8; ++k) {
        int c = k * 4 + w;                  // chunk 0..31, 1 KB each
        __builtin_amdgcn_global_load_lds(
            (const __attribute__((address_space(1))) void*)(g + c * 256 + lane * 4),
            (__attribute__((address_space(3))) void*)(row + c * 256),
            16, 0, 0);
    }
    __syncthreads();

    const int*   idxb = h ? hi_idx : lo_idx;
    const float* valb = h ? hi_val : lo_val;
    const int*   prow = pairs + r * CAP;

    for (int p = w; p < cnt; p += 4) {
        int t  = prow[p];
        int bb = t >> 10;
        int n  = nq[2 * bb + h];
        const int4*   idx4 = (const int4*)  (idxb + bb * LISTCAP);
        const float4* val4 = (const float4*)(valb + bb * LISTCAP);

        float acc = 0.f;
        #pragma unroll 2
        for (int q = 0; q < n; ++q) {       // avg ~2.5 iters
            int4   id = idx4[lane + q * 64];
            float4 v  = val4[lane + q * 64];
            acc += row[id.x] * v.x + row[id.y] * v.y
                 + row[id.z] * v.z + row[id.w] * v.w;
        }
        #pragma unroll
        for (int m = 32; m >= 1; m >>= 1) acc += __shfl_xor(acc, m, 64);
        if (lane == 0) part[h * NPAIRS + t] = acc;
    }
}

// ---------------- combine: out = lo + hi + bias -----------------------------

__global__ void combine_kernel(const float* __restrict__ part,
                               const float* __restrict__ bias,
                               const int*   __restrict__ out_idx,
                               float*       __restrict__ out) {
    int t = blockIdx.x * blockDim.x + threadIdx.x;
    out[t] = part[t] + part[NPAIRS + t] + bias[out_idx[t]];
}

// ---------------------------------------------------------------------------

extern "C" void kernel_launch(void* const* d_in, const int* in_sizes, int n_in,
                              void* d_out, int out_size, void* d_ws, size_t ws_size,
                              hipStream_t stream) {
    const float* in_vals = (const float*)d_in[0];   // (64,1024) f32
    const float* W       = (const float*)d_in[1];   // (16384,16384) f32
    const float* bias    = (const float*)d_in[2];   // (16384,) f32
    const int*   in_idx  = (const int*)  d_in[3];   // (64,1024) i32
    const int*   out_idx = (const int*)  d_in[4];   // (64,1024) i32
    float*       out     = (float*)d_out;           // (64,1024) f32

    // ws: cursor[16384] | pairs[16384*64] | lo_idx|hi_idx [64*1024] each |
    //     nq[128] | part[2*65536] | lo_val|hi_val [64*1024] each
    int*   cursor = (int*)d_ws;
    int*   pairs  = cursor + OUT_DIM;
    int*   lo_idx = pairs  + OUT_DIM * CAP;
    int*   hi_idx = lo_idx + BATCH * LISTCAP;
    int*   nq     = hi_idx + BATCH * LISTCAP;
    float* part   = (float*)(nq + 128);
    float* lo_val = part   + 2 * NPAIRS;
    float* hi_val = lo_val + BATCH * LISTCAP;

    zero_kernel     <<<OUT_DIM / 256, 256, 0, stream>>>(cursor, OUT_DIM);
    scatter_kernel  <<<NPAIRS / 256, 256, 0, stream>>>(out_idx, cursor, pairs);
    partition_kernel<<<BATCH, 64, 0, stream>>>(in_idx, in_vals,
                                               lo_idx, lo_val, hi_idx, hi_val, nq);
    slide_main      <<<2 * OUT_DIM, 256, 0, stream>>>(W, cursor, pairs,
                                                      lo_idx, lo_val, hi_idx, hi_val,
                                                      nq, part);
    combine_kernel  <<<NPAIRS / 256, 256, 0, stream>>>(part, bias, out_idx, out);
}

// Round 6
// 178.498 us; speedup vs baseline: 1.1968x; 1.1929x over previous
//
#include <hip/hip_runtime.h>

#define IN_DIM   16384
#define OUT_DIM  16384
#define BATCH    64
#define K_IN     1024
#define NPAIRS   65536
#define CAP      64        // bucket capacity per row (Poisson lambda=4, P(>64)~0)

// ---------------- prep: fixed-capacity bucket append ------------------------

__global__ void zero_kernel(int* __restrict__ p, int n) {
    int i = blockIdx.x * blockDim.x + threadIdx.x;
    if (i < n) p[i] = 0;
}

__global__ void scatter_kernel(const int* __restrict__ out_idx,
                               int* __restrict__ cursor,
                               int* __restrict__ pairs) {
    int t = blockIdx.x * blockDim.x + threadIdx.x;
    int r = out_idx[t];
    int pos = atomicAdd(&cursor[r], 1);
    if (pos < CAP) pairs[r * CAP + pos] = t;
}

// ---------------- main kernel: one block per W-row --------------------------
// Stage W[r,:] (64 KB) into LDS via async global_load_lds with the NT
// (non-temporal) cache hint so the zero-reuse W stream self-evicts from L2
// instead of sweeping out the reused idx/val/pairs metadata. Then each wave
// computes one (b,j) pair's dot via LDS gathers + shuffle reduction.

__launch_bounds__(512)
__global__ void slide_main(const float* __restrict__ in_vals,
                           const float* __restrict__ W,
                           const float* __restrict__ bias,
                           const int*   __restrict__ in_idx,
                           const int*   __restrict__ cnts,
                           const int*   __restrict__ pairs,
                           float*       __restrict__ out) {
    __shared__ float row[IN_DIM];   // 64 KB -> 2 blocks/CU
    int r   = blockIdx.x;
    int cnt = cnts[r];
    if (cnt == 0) return;           // unreferenced row: skip the 64 KB stream

    int w    = threadIdx.x >> 6;    // wave 0..7
    int lane = threadIdx.x & 63;

    float bv = bias[r];             // issue before stage; latency hides in drain

    // async stage: 8 waves x 8 issues x 1 KB = 64 KB, linear LDS layout, NT
    const float* g = W + (size_t)r * IN_DIM;
    #pragma unroll
    for (int k = 0; k < 8; ++k) {
        int off = (k * 8 + w) * 256;                       // floats
        __builtin_amdgcn_global_load_lds(
            (const __attribute__((address_space(1))) void*)(g + off + lane * 4),
            (__attribute__((address_space(3))) void*)(row + off),
            16, 0, /*aux=NT*/ 2);
    }
    __syncthreads();                // drains vmcnt

    const int* prow = pairs + (size_t)r * CAP;

    for (int p = w; p < cnt; p += 8) {
        int t  = prow[p];
        int bb = t >> 10;                                   // batch
        const int4*   idx4 = (const int4*)  (in_idx  + bb * K_IN);
        const float4* val4 = (const float4*)(in_vals + bb * K_IN);

        float acc = 0.f;
        #pragma unroll
        for (int i = 0; i < K_IN / 256; ++i) {              // 4 iters
            int4   id = idx4[lane + i * 64];                // coalesced, L2-hot
            float4 v  = val4[lane + i * 64];
            acc += row[id.x] * v.x + row[id.y] * v.y
                 + row[id.z] * v.z + row[id.w] * v.w;       // LDS gathers
        }
        #pragma unroll
        for (int m = 32; m >= 1; m >>= 1) acc += __shfl_xor(acc, m, 64);
        if (lane == 0) out[t] = acc + bv;
    }
}

// ---------------------------------------------------------------------------

extern "C" void kernel_launch(void* const* d_in, const int* in_sizes, int n_in,
                              void* d_out, int out_size, void* d_ws, size_t ws_size,
                              hipStream_t stream) {
    const float* in_vals = (const float*)d_in[0];   // (64,1024) f32
    const float* W       = (const float*)d_in[1];   // (16384,16384) f32
    const float* bias    = (const float*)d_in[2];   // (16384,) f32
    const int*   in_idx  = (const int*)  d_in[3];   // (64,1024) i32
    const int*   out_idx = (const int*)  d_in[4];   // (64,1024) i32
    float*       out     = (float*)d_out;           // (64,1024) f32

    // workspace (ints): cursor[OUT_DIM] | pairs[OUT_DIM*CAP]
    int* cursor = (int*)d_ws;
    int* pairs  = cursor + OUT_DIM;

    zero_kernel   <<<OUT_DIM / 256, 256, 0, stream>>>(cursor, OUT_DIM);
    scatter_kernel<<<NPAIRS / 256, 256, 0, stream>>>(out_idx, cursor, pairs);
    slide_main    <<<OUT_DIM, 512, 0, stream>>>(in_vals, W, bias, in_idx,
                                                cursor, pairs, out);
}

// Round 7
// 177.993 us; speedup vs baseline: 1.2001x; 1.0028x over previous
//
#include <hip/hip_runtime.h>

#define IN_DIM   16384
#define OUT_DIM  16384
#define BATCH    64
#define K_IN     1024
#define NPAIRS   65536
#define CAP      64        // bucket capacity per row (Poisson lambda=4, P(>64)~0)

// ---------------- prep: fixed-capacity bucket append ------------------------

__global__ void scatter_kernel(const int* __restrict__ out_idx,
                               int* __restrict__ cursor,
                               int* __restrict__ pairs) {
    int t = blockIdx.x * blockDim.x + threadIdx.x;
    int r = out_idx[t];
    int pos = atomicAdd(&cursor[r], 1);
    if (pos < CAP) pairs[r * CAP + pos] = t;
}

// ---------------- main kernel: one block per W-row --------------------------
// Stage W[r,:] (64 KB) into LDS via async global_load_lds with NT hint
// (zero-reuse stream self-evicts from L2; keeps idx/val metadata hot).
// prow/bias prefetched before the stage so the post-drain latency chain
// starts directly at the idx/val loads.

__launch_bounds__(512)
__global__ void slide_main(const float* __restrict__ in_vals,
                           const float* __restrict__ W,
                           const float* __restrict__ bias,
                           const int*   __restrict__ in_idx,
                           const int*   __restrict__ cnts,
                           const int*   __restrict__ pairs,
                           float*       __restrict__ out) {
    __shared__ float row[IN_DIM];   // 64 KB -> 2 blocks/CU
    int r   = blockIdx.x;
    int cnt = cnts[r];
    if (cnt == 0) return;           // unreferenced row: skip the 64 KB stream

    int w    = threadIdx.x >> 6;    // wave 0..7
    int lane = threadIdx.x & 63;

    float bv = bias[r];
    const int* prow = pairs + (size_t)r * CAP;
    int p0 = (w < cnt) ? w : cnt - 1;
    int t0 = prow[p0];              // prefetch: retired by the stage drain

    // async stage: 8 waves x 8 issues x 1 KB = 64 KB, linear LDS layout, NT
    const float* g = W + (size_t)r * IN_DIM;
    #pragma unroll
    for (int k = 0; k < 8; ++k) {
        int off = (k * 8 + w) * 256;                       // floats
        __builtin_amdgcn_global_load_lds(
            (const __attribute__((address_space(1))) void*)(g + off + lane * 4),
            (__attribute__((address_space(3))) void*)(row + off),
            16, 0, /*aux=NT*/ 2);
    }
    __syncthreads();                // drains vmcnt

    for (int p = w; p < cnt; p += 8) {
        int t  = (p == w) ? t0 : prow[p];
        int bb = t >> 10;                                   // batch
        const int4*   idx4 = (const int4*)  (in_idx  + bb * K_IN);
        const float4* val4 = (const float4*)(in_vals + bb * K_IN);

        float acc = 0.f;
        #pragma unroll
        for (int i = 0; i < K_IN / 256; ++i) {              // 4 iters
            int4   id = idx4[lane + i * 64];                // coalesced, L2-hot
            float4 v  = val4[lane + i * 64];
            acc += row[id.x] * v.x + row[id.y] * v.y
                 + row[id.z] * v.z + row[id.w] * v.w;       // LDS gathers
        }
        #pragma unroll
        for (int m = 32; m >= 1; m >>= 1) acc += __shfl_xor(acc, m, 64);
        if (lane == 0) out[t] = acc + bv;
    }
}

// ---------------------------------------------------------------------------

extern "C" void kernel_launch(void* const* d_in, const int* in_sizes, int n_in,
                              void* d_out, int out_size, void* d_ws, size_t ws_size,
                              hipStream_t stream) {
    const float* in_vals = (const float*)d_in[0];   // (64,1024) f32
    const float* W       = (const float*)d_in[1];   // (16384,16384) f32
    const float* bias    = (const float*)d_in[2];   // (16384,) f32
    const int*   in_idx  = (const int*)  d_in[3];   // (64,1024) i32
    const int*   out_idx = (const int*)  d_in[4];   // (64,1024) i32
    float*       out     = (float*)d_out;           // (64,1024) f32

    // workspace (ints): cursor[OUT_DIM] | pairs[OUT_DIM*CAP]
    int* cursor = (int*)d_ws;
    int* pairs  = cursor + OUT_DIM;

    hipMemsetAsync(cursor, 0, OUT_DIM * sizeof(int), stream);
    scatter_kernel<<<NPAIRS / 256, 256, 0, stream>>>(out_idx, cursor, pairs);
    slide_main    <<<OUT_DIM, 512, 0, stream>>>(in_vals, W, bias, in_idx,
                                                cursor, pairs, out);
}